// Round 4
// baseline (396.626 us; speedup 1.0000x reference)
//
#include <hip/hip_runtime.h>
#include <hip/hip_bf16.h>

// Problem constants
#define NB 64   // batch N
#define CC 64   // in channels C
#define TT 256  // time T
#define VV 25   // vertices V (= U)
#define HH 8    // heads H
#define OO 64   // out channels O
#define TV (TT*VV)   // 6400
#define UV (VV*VV)   // 625
#define NCHUNK 25    // tv-chunks of 256 per n  (25*256 == TV)

// ---------------------------------------------------------------------------
// Kernel P: transpose Wv -> WvT[c][o]  (contiguous per-c rows -> wave-uniform
// scalar loads in k_vmean's inner loop). grid = 16 blocks.
// ---------------------------------------------------------------------------
__global__ __launch_bounds__(256) void k_prep(const float* __restrict__ Wv,
                                              float* __restrict__ WvT) {
    int i = blockIdx.x * 256 + threadIdx.x;   // 0..4095
    int o = i >> 6, c = i & 63;
    WvT[c * OO + o] = Wv[o * CC + c];
}

// ---------------------------------------------------------------------------
// Kernel VM: fused v-projection + x temporal partial-sum. Reads x from HBM
// exactly once (the only full x pass in the pipeline).
//   vv[n,o,t,v]        = sum_c Wv[o,c]*x[n,c,t,v] + bv[o]   -> into d_out
//   xpart[n,ch,c*25+v] = sum_{tv in chunk} x[n,c,tv]        -> plain stores
// grid = N*25 = 1600 blocks, 256 threads; thread = one tv position, all 64 o
// accumulated in registers. Weights wave-uniform -> SGPR loads. VALU-bound.
// No atomics anywhere -> fully deterministic.
// ---------------------------------------------------------------------------
__global__ __launch_bounds__(256) void k_vmean(const float* __restrict__ x,
                                               const float* __restrict__ WvT,
                                               const float* __restrict__ bv,
                                               float* __restrict__ vv,
                                               float* __restrict__ xpart) {
    int blk = blockIdx.x;
    int n = blk / NCHUNK, ch = blk % NCHUNK;
    int tid = threadIdx.x;
    int tv = ch * 256 + tid;
    int vloc = tv % VV;

    __shared__ float xacc[CC * VV];          // 6.4 KB
    for (int i = tid; i < CC * VV; i += 256) xacc[i] = 0.0f;
    __syncthreads();

    const float*  xs  = x + (size_t)n * CC * TV + tv;
    const float2* W2  = (const float2*)WvT;  // [c][o/2], 8B-aligned
    const float2* bv2 = (const float2*)bv;

    float2 acc[OO / 2];
#pragma unroll
    for (int j = 0; j < OO / 2; ++j) acc[j] = bv2[j];

#pragma unroll 2
    for (int c = 0; c < CC; ++c) {
        float xv = xs[(size_t)c * TV];          // coalesced 1KB/wave
        atomicAdd(&xacc[c * VV + vloc], xv);    // ds_add_f32, ~3-way same-addr
#pragma unroll
        for (int j = 0; j < OO / 2; ++j) {
            float2 w = W2[c * (OO / 2) + j];    // wave-uniform -> SGPR
            acc[j].x += w.x * xv;
            acc[j].y += w.y * xv;
        }
    }

    float* dst = vv + (size_t)n * OO * TV + tv;
#pragma unroll
    for (int j = 0; j < OO / 2; ++j) {
        dst[(size_t)(2 * j) * TV]     = acc[j].x;   // coalesced
        dst[(size_t)(2 * j + 1) * TV] = acc[j].y;
    }

    __syncthreads();                               // xacc complete
    float* xg = xpart + (size_t)blk * (CC * VV);   // this block's private slab
    for (int i = tid; i < CC * VV; i += 256) xg[i] = xacc[i];  // coalesced
}

// ---------------------------------------------------------------------------
// Kernel B: reduce xpart -> xmean (in LDS), then
//   masked[n,o,u,v] = alpha*(sum_h Wr[o,h]*tanh(q[u]-k[v]) + br[o]) + A[u,v]
// masked is written OVER the xpart region of the same n (read fully before
// write, separated by __syncthreads; blocks touch disjoint 40000-fl regions).
// grid = N blocks. ~3-4 us.
// ---------------------------------------------------------------------------
__global__ __launch_bounds__(256) void k_masked(
        float* __restrict__ buf,   // in: xpart[n][25][1600]; out: masked[n][40000]
        const float* __restrict__ A,
        const float* __restrict__ alpha_p,
        const float* __restrict__ Wq, const float* __restrict__ bq,
        const float* __restrict__ Wk, const float* __restrict__ bk,
        const float* __restrict__ Wr, const float* __restrict__ br) {
    int n = blockIdx.x, tid = threadIdx.x;
    __shared__ float xm[CC * VV];          // mean
    __shared__ float qs[HH * VV];
    __shared__ float ks[HH * VV];
    __shared__ float attn[HH * UV];

    const float* xp = buf + (size_t)n * (NCHUNK * CC * VV);
    for (int i = tid; i < CC * VV; i += 256) {
        float s = 0.0f;
#pragma unroll
        for (int ch = 0; ch < NCHUNK; ++ch) s += xp[ch * (CC * VV) + i];
        xm[i] = s * (1.0f / TT);
    }
    __syncthreads();

    for (int i = tid; i < 2 * HH * VV; i += 256) {   // 400 q/k outputs
        int isK = i >= HH * VV;
        int hv = isK ? i - HH * VV : i;
        int h = hv / VV, v = hv % VV;
        const float* W = isK ? Wk : Wq;
        float s = isK ? bk[h] : bq[h];
        for (int c = 0; c < CC; ++c) s += xm[c * VV + v] * W[h * CC + c];
        if (isK) ks[hv] = s; else qs[hv] = s;
    }
    __syncthreads();

    for (int i = tid; i < HH * UV; i += 256) {       // 5000 tanh
        int h = i / UV, uv = i % UV, u = uv / VV, v = uv % VV;
        attn[i] = tanhf(qs[h * VV + u] - ks[h * VV + v]);
    }
    __syncthreads();

    float alpha = alpha_p[0];
    float* mout = buf + (size_t)n * (OO * UV);       // same region, now output
    for (int i = tid; i < OO * UV; i += 256) {       // 40000 masked outputs
        int o = i / UV, uv = i % UV;
        float r = br[o];
#pragma unroll
        for (int h = 0; h < HH; ++h) r += Wr[o * HH + h] * attn[h * UV + uv];
        mout[i] = alpha * r + A[uv];
    }
}

// ---------------------------------------------------------------------------
// Kernel C: aggregation, in-place on d_out, LDS-staged for coalescing.
// out[n,o,t,u] = sum_v masked[n,o,u,v] * vv[n,o,t,v]
// grid = N*O blocks, 256 threads (thread = t). float4 coalesced global IO;
// per-thread LDS rows at stride 25 (odd -> <=2 lanes/bank, free per m136).
// masked row is block-uniform -> scalar loads. HBM-write-bound.
// ---------------------------------------------------------------------------
__global__ __launch_bounds__(256) void k_aggr(float* __restrict__ io,
                                              const float* __restrict__ masked) {
    int no = blockIdx.x;                  // n*64 + o
    int t  = threadIdx.x;
    __shared__ float buf[TV];             // 25.6 KB
    float4* b4 = (float4*)buf;
    float4* g4 = (float4*)(io + (size_t)no * TV);

    for (int i = t; i < TV / 4; i += 256) b4[i] = g4[i];   // coalesced in
    __syncthreads();

    float xv[VV];
#pragma unroll
    for (int v = 0; v < VV; ++v) xv[v] = buf[t * VV + v];

    const float* m = masked + (size_t)no * UV;   // block-uniform -> SGPR
    float outr[VV];
#pragma unroll
    for (int u = 0; u < VV; ++u) {
        float a = 0.0f;
#pragma unroll
        for (int v = 0; v < VV; ++v) a += m[u * VV + v] * xv[v];
        outr[u] = a;
    }
#pragma unroll
    for (int u = 0; u < VV; ++u) buf[t * VV + u] = outr[u];  // own row only
    __syncthreads();

    for (int i = t; i < TV / 4; i += 256) g4[i] = b4[i];   // coalesced out
}

// ---------------------------------------------------------------------------
extern "C" void kernel_launch(void* const* d_in, const int* in_sizes, int n_in,
                              void* d_out, int out_size, void* d_ws, size_t ws_size,
                              hipStream_t stream) {
    const float* x     = (const float*)d_in[0];
    const float* A     = (const float*)d_in[1];
    const float* alpha = (const float*)d_in[2];
    const float* Wq    = (const float*)d_in[3];
    const float* bq    = (const float*)d_in[4];
    const float* Wk    = (const float*)d_in[5];
    const float* bk    = (const float*)d_in[6];
    const float* Wv    = (const float*)d_in[7];
    const float* bv    = (const float*)d_in[8];
    const float* Wr    = (const float*)d_in[9];
    const float* br    = (const float*)d_in[10];
    float* out = (float*)d_out;

    // ws layout: [ xpart -> overwritten in place by masked : 2,560,000 fl ]
    //            [ WvT : 4,096 fl ]            total ~10.26 MB
    float* ws     = (float*)d_ws;
    float* xpart  = ws;                        // N*25*1600 == N*O*UV == 2.56M fl
    float* masked = ws;                        // same region, after k_masked
    float* WvT    = ws + (size_t)NB * OO * UV;

    k_prep  <<<(CC * OO) / 256, 256, 0, stream>>>(Wv, WvT);
    k_vmean <<<NB * NCHUNK, 256, 0, stream>>>(x, WvT, bv, out, xpart);
    k_masked<<<NB, 256, 0, stream>>>(masked, A, alpha, Wq, bq, Wk, bk, Wr, br);
    k_aggr  <<<NB * OO, 256, 0, stream>>>(out, masked);
}

// Round 5
// 337.784 us; speedup vs baseline: 1.1742x; 1.1742x over previous
//
#include <hip/hip_runtime.h>
#include <hip/hip_bf16.h>

// Problem constants
#define NB 64   // batch N
#define CC 64   // in channels C
#define TT 256  // time T
#define VV 25   // vertices V (= U)
#define HH 8    // heads H
#define OO 64   // out channels O
#define TV (TT*VV)   // 6400
#define UV (VV*VV)   // 625

// ---------------------------------------------------------------------------
// Kernel P: transpose Wv -> WvT[c][o]  (contiguous per-c rows -> wave-uniform
// scalar loads in k_vproj's inner loop). grid = 16 blocks.
// ---------------------------------------------------------------------------
__global__ __launch_bounds__(256) void k_prep(const float* __restrict__ Wv,
                                              float* __restrict__ WvT) {
    int i = blockIdx.x * 256 + threadIdx.x;   // 0..4095
    int o = i >> 6, c = i & 63;
    WvT[c * OO + o] = Wv[o * CC + c];
}

// ---------------------------------------------------------------------------
// Kernel V: pure v-projection. vv[n,o,t,v] = sum_c Wv[o,c]*x[n,c,t,v] + bv[o]
// Written into d_out. grid = N*25 = 1600 blocks, 256 threads; thread = one tv
// position, ALL 64 o in 16 float4 registers.
// __launch_bounds__(256,4): explicit 128-VGPR budget so the backend does NOT
// remat/re-read x to chase 8-waves occupancy (round-4 pathology: VGPR=40,
// VALUBusy=13%). No atomics, no LDS: per c-quad = 4 coalesced loads + 256
// v_fmac_f32 with SGPR weight operands.
// ---------------------------------------------------------------------------
__global__ __launch_bounds__(256, 4) void k_vproj(const float* __restrict__ x,
                                                  const float* __restrict__ WvT,
                                                  const float* __restrict__ bv,
                                                  float* __restrict__ vv) {
    int blk = blockIdx.x;
    int n = blk / 25, ch = blk % 25;
    int tv = ch * 256 + threadIdx.x;

    const float*  xs = x + (size_t)n * CC * TV + tv;
    const float4* W4 = (const float4*)WvT;      // [c][o/4], 16B-aligned
    const float4* b4 = (const float4*)bv;

    float4 a[OO / 4];                            // 64 accs, static indices only
#pragma unroll
    for (int j = 0; j < OO / 4; ++j) a[j] = b4[j];

    for (int c = 0; c < CC; c += 4) {            // 16 iterations
        float x0 = xs[(size_t)(c + 0) * TV];     // 4 independent coalesced
        float x1 = xs[(size_t)(c + 1) * TV];     // loads in flight
        float x2 = xs[(size_t)(c + 2) * TV];
        float x3 = xs[(size_t)(c + 3) * TV];
#pragma unroll
        for (int j = 0; j < OO / 4; ++j) {       // uniform -> s_load weights
            float4 w0 = W4[(c + 0) * (OO / 4) + j];
            float4 w1 = W4[(c + 1) * (OO / 4) + j];
            float4 w2 = W4[(c + 2) * (OO / 4) + j];
            float4 w3 = W4[(c + 3) * (OO / 4) + j];
            a[j].x += w0.x * x0; a[j].y += w0.y * x0; a[j].z += w0.z * x0; a[j].w += w0.w * x0;
            a[j].x += w1.x * x1; a[j].y += w1.y * x1; a[j].z += w1.z * x1; a[j].w += w1.w * x1;
            a[j].x += w2.x * x2; a[j].y += w2.y * x2; a[j].z += w2.z * x2; a[j].w += w2.w * x2;
            a[j].x += w3.x * x3; a[j].y += w3.y * x3; a[j].z += w3.z * x3; a[j].w += w3.w * x3;
        }
    }

    float* dst = vv + (size_t)n * OO * TV + tv;
#pragma unroll
    for (int j = 0; j < OO / 4; ++j) {           // coalesced per-o-plane stores
        dst[(size_t)(4 * j + 0) * TV] = a[j].x;
        dst[(size_t)(4 * j + 1) * TV] = a[j].y;
        dst[(size_t)(4 * j + 2) * TV] = a[j].z;
        dst[(size_t)(4 * j + 3) * TV] = a[j].w;
    }
}

// ---------------------------------------------------------------------------
// Kernel M: x temporal mean. Runs AFTER k_vproj so x is L3-resident.
// grid = N*C = 4096 blocks, 256 threads. Stage the 25.6 KB row coalesced
// (float4) into LDS, column-reduce in LDS (stride-25 odd -> <=3 lanes/bank).
// ---------------------------------------------------------------------------
__global__ __launch_bounds__(256) void k_mean(const float* __restrict__ x,
                                              float* __restrict__ xmean) {
    int nc  = blockIdx.x;
    int tid = threadIdx.x;
    __shared__ float tile[TV];                 // 25.6 KB
    __shared__ float part[8 * VV];

    const float4* g4 = (const float4*)(x + (size_t)nc * TV);
    float4*       t4 = (float4*)tile;
    for (int i = tid; i < TV / 4; i += 256) t4[i] = g4[i];   // coalesced
    __syncthreads();

    if (tid < 8 * VV) {                        // 200 active: g=0..7, v=0..24
        int g = tid / VV, v = tid % VV;
        float s = 0.0f;
#pragma unroll
        for (int j = 0; j < 32; ++j) s += tile[(g * 32 + j) * VV + v];
        part[g * VV + v] = s;
    }
    __syncthreads();

    if (tid < VV) {
        float s = 0.0f;
#pragma unroll
        for (int g = 0; g < 8; ++g) s += part[g * VV + tid];
        xmean[(size_t)nc * VV + tid] = s * (1.0f / TT);
    }
}

// ---------------------------------------------------------------------------
// Kernel B: masked[n,o,u,v] =
//     alpha*(sum_h Wr[o,h]*tanh(q[n,h,u]-k[n,h,v]) + br[o]) + A[u,v]
// grid = N blocks. ~3-5 us.
// ---------------------------------------------------------------------------
__global__ __launch_bounds__(256) void k_masked(
        const float* __restrict__ xmean, const float* __restrict__ A,
        const float* __restrict__ alpha_p,
        const float* __restrict__ Wq, const float* __restrict__ bq,
        const float* __restrict__ Wk, const float* __restrict__ bk,
        const float* __restrict__ Wr, const float* __restrict__ br,
        float* __restrict__ masked) {
    int n = blockIdx.x, tid = threadIdx.x;
    __shared__ float xm[CC * VV];
    __shared__ float qs[HH * VV];
    __shared__ float ks[HH * VV];
    __shared__ float attn[HH * UV];

    for (int i = tid; i < CC * VV; i += 256)
        xm[i] = xmean[(size_t)n * CC * VV + i];
    __syncthreads();

    for (int i = tid; i < 2 * HH * VV; i += 256) {   // 400 q/k outputs
        int isK = i >= HH * VV;
        int hv = isK ? i - HH * VV : i;
        int h = hv / VV, v = hv % VV;
        const float* W = isK ? Wk : Wq;
        float s = isK ? bk[h] : bq[h];
        for (int c = 0; c < CC; ++c) s += xm[c * VV + v] * W[h * CC + c];
        if (isK) ks[hv] = s; else qs[hv] = s;
    }
    __syncthreads();

    for (int i = tid; i < HH * UV; i += 256) {       // 5000 tanh
        int h = i / UV, uv = i % UV, u = uv / VV, v = uv % VV;
        attn[i] = tanhf(qs[h * VV + u] - ks[h * VV + v]);
    }
    __syncthreads();

    float alpha = alpha_p[0];
    for (int i = tid; i < OO * UV; i += 256) {       // 40000 masked outputs
        int o = i / UV, uv = i % UV;
        float r = br[o];
#pragma unroll
        for (int h = 0; h < HH; ++h) r += Wr[o * HH + h] * attn[h * UV + uv];
        masked[(size_t)n * OO * UV + i] = alpha * r + A[uv];
    }
}

// ---------------------------------------------------------------------------
// Kernel C: aggregation, in-place on d_out, LDS-staged for coalescing.
// out[n,o,t,u] = sum_v masked[n,o,u,v] * vv[n,o,t,v]
// grid = N*O blocks, 256 threads (thread = t). float4 coalesced global IO;
// LDS rows at stride 25 (odd -> 2 lanes/bank, free). masked row block-uniform
// -> scalar loads. HBM-write-bound (~17-20 us).
// ---------------------------------------------------------------------------
__global__ __launch_bounds__(256) void k_aggr(float* __restrict__ io,
                                              const float* __restrict__ masked) {
    int no = blockIdx.x;                  // n*64 + o
    int t  = threadIdx.x;
    __shared__ float buf[TV];             // 25.6 KB
    float4* b4 = (float4*)buf;
    float4* g4 = (float4*)(io + (size_t)no * TV);

    for (int i = t; i < TV / 4; i += 256) b4[i] = g4[i];   // coalesced in
    __syncthreads();

    float xv[VV];
#pragma unroll
    for (int v = 0; v < VV; ++v) xv[v] = buf[t * VV + v];

    const float* m = masked + (size_t)no * UV;   // block-uniform -> SGPR
    float outr[VV];
#pragma unroll
    for (int u = 0; u < VV; ++u) {
        float a = 0.0f;
#pragma unroll
        for (int v = 0; v < VV; ++v) a += m[u * VV + v] * xv[v];
        outr[u] = a;
    }
#pragma unroll
    for (int u = 0; u < VV; ++u) buf[t * VV + u] = outr[u];  // own row only
    __syncthreads();

    for (int i = t; i < TV / 4; i += 256) g4[i] = b4[i];   // coalesced out
}

// ---------------------------------------------------------------------------
extern "C" void kernel_launch(void* const* d_in, const int* in_sizes, int n_in,
                              void* d_out, int out_size, void* d_ws, size_t ws_size,
                              hipStream_t stream) {
    const float* x     = (const float*)d_in[0];
    const float* A     = (const float*)d_in[1];
    const float* alpha = (const float*)d_in[2];
    const float* Wq    = (const float*)d_in[3];
    const float* bq    = (const float*)d_in[4];
    const float* Wk    = (const float*)d_in[5];
    const float* bk    = (const float*)d_in[6];
    const float* Wv    = (const float*)d_in[7];
    const float* bv    = (const float*)d_in[8];
    const float* Wr    = (const float*)d_in[9];
    const float* br    = (const float*)d_in[10];
    float* out = (float*)d_out;

    // ws layout: masked 2,560,000 fl | xmean 102,400 fl | WvT 4,096 fl (~10.7 MB)
    float* ws     = (float*)d_ws;
    float* masked = ws;
    float* xmean  = ws + (size_t)NB * OO * UV;
    float* WvT    = xmean + (size_t)NB * CC * VV;

    k_prep  <<<(CC * OO) / 256, 256, 0, stream>>>(Wv, WvT);
    k_vproj <<<NB * 25, 256, 0, stream>>>(x, WvT, bv, out);
    k_mean  <<<NB * CC, 256, 0, stream>>>(x, xmean);   // x L3-resident now
    k_masked<<<NB, 256, 0, stream>>>(xmean, A, alpha, Wq, bq, Wk, bk, Wr, br, masked);
    k_aggr  <<<NB * OO, 256, 0, stream>>>(out, masked);
}